// Round 1
// baseline (489.274 us; speedup 1.0000x reference)
//
#include <hip/hip_runtime.h>
#include <hip/hip_bf16.h>
#include <stdint.h>

typedef _Float16 half_t;
typedef _Float16 half4 __attribute__((ext_vector_type(4)));
typedef _Float16 half8 __attribute__((ext_vector_type(8)));
typedef float f32x4 __attribute__((ext_vector_type(4)));

#define SCALE_ 0.03125f   // 1/sqrt(1024)

// async global->LDS, 16B per lane, wave-uniform LDS base + lane*16
#define GLL16(g, l)                                                        \
  __builtin_amdgcn_global_load_lds(                                        \
      (const __attribute__((address_space(1))) void*)(g),                  \
      (__attribute__((address_space(3))) void*)(l), 16, 0, 0)

// ---------------------------------------------------------------- converts
__global__ void cvt_f32_f16(const float* __restrict__ in,
                            half_t* __restrict__ out, int n4) {
  int i = blockIdx.x * blockDim.x + threadIdx.x;
  if (i < n4) {
    float4 v = ((const float4*)in)[i];
    half4 h;
    h[0] = (half_t)v.x; h[1] = (half_t)v.y; h[2] = (half_t)v.z; h[3] = (half_t)v.w;
    ((half4*)out)[i] = h;
  }
}

// ---------------------------------------------------------------- QKV GEMM
// A = xb [4096][1024] f16, Bw = w_qkv f16 [3072][1024] (N x K, B^T form)
// C[m,n] = sum_k A[m,k]*Bw[n,k] + bias[n]; scatter into Qh/Kh (scaled) and Vt.
__global__ __launch_bounds__(256) void qkv_gemm(
    const half_t* __restrict__ A, const half_t* __restrict__ Bw,
    const float* __restrict__ bias,
    half_t* __restrict__ Qh, half_t* __restrict__ Kh, half_t* __restrict__ Vt) {
  __shared__ __align__(16) half_t As[128 * 32];
  __shared__ __align__(16) half_t Bs[128 * 32];
  const int tid = threadIdx.x;
  const int wave = tid >> 6, lane = tid & 63;
  const int t = lane & 15, g = lane >> 4;
  const int wr = (wave >> 1) * 64, wc = (wave & 1) * 64;
  const int m0 = blockIdx.y * 128, n0 = blockIdx.x * 128;

  f32x4 acc[4][4];
#pragma unroll
  for (int i = 0; i < 4; ++i)
#pragma unroll
    for (int j = 0; j < 4; ++j) acc[i][j] = (f32x4){0.f, 0.f, 0.f, 0.f};

  const int srow = tid >> 2, schunk = (tid & 3) * 8;
  const half_t* aptr = A + (size_t)(m0 + srow) * 1024 + schunk;
  const half_t* bptr = Bw + (size_t)(n0 + srow) * 1024 + schunk;
  char* asb = (char*)As + wave * 1024;
  char* bsb = (char*)Bs + wave * 1024;

  for (int kk = 0; kk < 1024; kk += 32) {
    GLL16(aptr, asb);
    GLL16(aptr + 64 * 1024, asb + 4096);
    GLL16(bptr, bsb);
    GLL16(bptr + 64 * 1024, bsb + 4096);
    aptr += 32; bptr += 32;
    __syncthreads();

    half8 af[4], bf[4];
#pragma unroll
    for (int fm = 0; fm < 4; ++fm)
      af[fm] = *(const half8*)&As[(wr + fm * 16 + t) * 32 + g * 8];
#pragma unroll
    for (int fn = 0; fn < 4; ++fn)
      bf[fn] = *(const half8*)&Bs[(wc + fn * 16 + t) * 32 + g * 8];
#pragma unroll
    for (int fm = 0; fm < 4; ++fm)
#pragma unroll
      for (int fn = 0; fn < 4; ++fn)
        acc[fm][fn] = __builtin_amdgcn_mfma_f32_16x16x32_f16(
            af[fm], bf[fn], acc[fm][fn], 0, 0, 0);
    __syncthreads();
  }

  // epilogue: D col = lane&15, row = (lane>>4)*4 + reg  [verified mapping]
#pragma unroll
  for (int fm = 0; fm < 4; ++fm) {
    const int mb = m0 + wr + fm * 16 + g * 4;
#pragma unroll
    for (int fn = 0; fn < 4; ++fn) {
      const int n = n0 + wc + fn * 16 + t;
      const float bv = bias[n];
      const int sec = n >> 10, nn = n & 1023;
      const int h = nn >> 6, c = nn & 63;
#pragma unroll
      for (int r = 0; r < 4; ++r) {
        const int mm = mb + r;
        const int b = mm >> 11, l = mm & 2047;
        const float v = acc[fm][fn][r] + bv;
        const size_t bh = (size_t)(b * 16 + h);
        if (sec == 0)      Qh[(bh * 2048 + l) * 64 + c] = (half_t)(v * SCALE_);
        else if (sec == 1) Kh[(bh * 2048 + l) * 64 + c] = (half_t)v;
        else               Vt[(bh * 64 + c) * 2048 + l] = (half_t)v;
      }
    }
  }
}

// ---------------------------------------------------------------- attention
// Qh/Kh: [32][2048][64] f16 (Q pre-scaled); Vt: [32][64][2048] f16
// Hd out: [4096][1024] f16  (heads, [b*l][h*64+c])
__global__ __launch_bounds__(256) void attn_kernel(
    const half_t* __restrict__ Qh, const half_t* __restrict__ Kh,
    const half_t* __restrict__ Vt, half_t* __restrict__ Hd) {
  const int bh = blockIdx.x;   // 0..31  (b*16+h)
  const int qt = blockIdx.y;   // 0..31  (64 q rows each)
  const int wave = threadIdx.x >> 6, lane = threadIdx.x & 63;
  const int t = lane & 15, g = lane >> 4;

  const half_t* Q = Qh + ((size_t)bh * 2048 + qt * 64 + wave * 16) * 64;
  const half_t* K = Kh + (size_t)bh * 2048 * 64;
  const half_t* V = Vt + (size_t)bh * 64 * 2048;

  // Q fragments: B-operand of S^T mfma: lane holds Q[q=t][c=g*8+j]
  const half8 q0 = *(const half8*)&Q[t * 64 + g * 8];
  const half8 q1 = *(const half8*)&Q[t * 64 + 32 + g * 8];

  f32x4 o[4];
#pragma unroll
  for (int i = 0; i < 4; ++i) o[i] = (f32x4){0.f, 0.f, 0.f, 0.f};
  float m_run = -1e30f, l_run = 0.f;

  for (int mt = 0; mt < 2048; mt += 64) {
    // S^T = K * Q^T : D[row=m][col=q]
    f32x4 s[4];
#pragma unroll
    for (int st = 0; st < 4; ++st) {
      const half_t* Krow = K + (size_t)(mt + st * 16 + t) * 64;
      half8 k0 = *(const half8*)&Krow[g * 8];
      half8 k1 = *(const half8*)&Krow[32 + g * 8];
      f32x4 a = (f32x4){0.f, 0.f, 0.f, 0.f};
      a = __builtin_amdgcn_mfma_f32_16x16x32_f16(k0, q0, a, 0, 0, 0);
      a = __builtin_amdgcn_mfma_f32_16x16x32_f16(k1, q1, a, 0, 0, 0);
      s[st] = a;
    }
    // per-q-col (lane&15) max over the 64 m of this tile
    float tm = -1e30f;
#pragma unroll
    for (int st = 0; st < 4; ++st)
#pragma unroll
      for (int r = 0; r < 4; ++r) tm = fmaxf(tm, s[st][r]);
    tm = fmaxf(tm, __shfl_xor(tm, 16));
    tm = fmaxf(tm, __shfl_xor(tm, 32));

    const float mnew = fmaxf(m_run, tm);
    const float corr = __expf(m_run - mnew);
    m_run = mnew;

    float rs = 0.f;
    half4 pf[4];
#pragma unroll
    for (int st = 0; st < 4; ++st)
#pragma unroll
      for (int r = 0; r < 4; ++r) {
        const float p = __expf(s[st][r] - mnew);
        rs += p;
        pf[st][r] = (half_t)p;
      }
    rs += __shfl_xor(rs, 16);
    rs += __shfl_xor(rs, 32);
    l_run = l_run * corr + rs;

    // rescale O (O row q = g*4+r lives at col-lane q -> shfl from lane q)
#pragma unroll
    for (int r = 0; r < 4; ++r) {
      const float cv = __shfl(corr, (g << 2) + r);
#pragma unroll
      for (int ct = 0; ct < 4; ++ct) o[ct][r] *= cv;
    }
    // PV: D[row=q][col=c] += P * V  (A = P in-lane, B = Vt rows, contiguous)
#pragma unroll
    for (int st = 0; st < 4; ++st)
#pragma unroll
      for (int ct = 0; ct < 4; ++ct) {
        half4 vf = *(const half4*)&V[(size_t)(ct * 16 + t) * 2048 + mt + st * 16 + g * 4];
        o[ct] = __builtin_amdgcn_mfma_f32_16x16x16f16(pf[st], vf, o[ct], 0, 0, 0);
      }
  }

  const int b = bh >> 4, h = bh & 15;
#pragma unroll
  for (int r = 0; r < 4; ++r) {
    const float li = 1.f / __shfl(l_run, (g << 2) + r);
    const size_t row = (size_t)b * 2048 + qt * 64 + wave * 16 + g * 4 + r;
#pragma unroll
    for (int ct = 0; ct < 4; ++ct)
      Hd[row * 1024 + h * 64 + ct * 16 + t] = (half_t)(o[ct][r] * li);
  }
}

// ---------------------------------------------------------------- out GEMM
// out[m,n] = sum_k Hd[m,k]*wob[n,k] + b_o[n] + x[m,n]   (fp32 out)
__global__ __launch_bounds__(256) void out_gemm(
    const half_t* __restrict__ A, const half_t* __restrict__ Bw,
    const float* __restrict__ bias, const float* __restrict__ xres,
    float* __restrict__ out) {
  __shared__ __align__(16) half_t As[128 * 32];
  __shared__ __align__(16) half_t Bs[128 * 32];
  const int tid = threadIdx.x;
  const int wave = tid >> 6, lane = tid & 63;
  const int t = lane & 15, g = lane >> 4;
  const int wr = (wave >> 1) * 64, wc = (wave & 1) * 64;
  const int m0 = blockIdx.y * 128, n0 = blockIdx.x * 128;

  f32x4 acc[4][4];
#pragma unroll
  for (int i = 0; i < 4; ++i)
#pragma unroll
    for (int j = 0; j < 4; ++j) acc[i][j] = (f32x4){0.f, 0.f, 0.f, 0.f};

  const int srow = tid >> 2, schunk = (tid & 3) * 8;
  const half_t* aptr = A + (size_t)(m0 + srow) * 1024 + schunk;
  const half_t* bptr = Bw + (size_t)(n0 + srow) * 1024 + schunk;
  char* asb = (char*)As + wave * 1024;
  char* bsb = (char*)Bs + wave * 1024;

  for (int kk = 0; kk < 1024; kk += 32) {
    GLL16(aptr, asb);
    GLL16(aptr + 64 * 1024, asb + 4096);
    GLL16(bptr, bsb);
    GLL16(bptr + 64 * 1024, bsb + 4096);
    aptr += 32; bptr += 32;
    __syncthreads();

    half8 af[4], bf[4];
#pragma unroll
    for (int fm = 0; fm < 4; ++fm)
      af[fm] = *(const half8*)&As[(wr + fm * 16 + t) * 32 + g * 8];
#pragma unroll
    for (int fn = 0; fn < 4; ++fn)
      bf[fn] = *(const half8*)&Bs[(wc + fn * 16 + t) * 32 + g * 8];
#pragma unroll
    for (int fm = 0; fm < 4; ++fm)
#pragma unroll
      for (int fn = 0; fn < 4; ++fn)
        acc[fm][fn] = __builtin_amdgcn_mfma_f32_16x16x32_f16(
            af[fm], bf[fn], acc[fm][fn], 0, 0, 0);
    __syncthreads();
  }

#pragma unroll
  for (int fm = 0; fm < 4; ++fm) {
    const int mb = m0 + wr + fm * 16 + g * 4;
#pragma unroll
    for (int fn = 0; fn < 4; ++fn) {
      const int n = n0 + wc + fn * 16 + t;
      const float bv = bias[n];
#pragma unroll
      for (int r = 0; r < 4; ++r) {
        const size_t idx = (size_t)(mb + r) * 1024 + n;
        out[idx] = acc[fm][fn][r] + bv + xres[idx];
      }
    }
  }
}

// ---------------------------------------------------------------- launch
extern "C" void kernel_launch(void* const* d_in, const int* in_sizes, int n_in,
                              void* d_out, int out_size, void* d_ws, size_t ws_size,
                              hipStream_t stream) {
  const float* x     = (const float*)d_in[0];
  const float* w_qkv = (const float*)d_in[1];
  const float* b_qkv = (const float*)d_in[2];
  const float* w_o   = (const float*)d_in[3];
  const float* b_o   = (const float*)d_in[4];
  float* out = (float*)d_out;

  char* ws = (char*)d_ws;
  half_t* xb    = (half_t*)(ws + 0);                  // 8 MB
  half_t* wqkvb = (half_t*)(ws + (size_t)8  * 1048576);  // 6 MB
  half_t* wob   = (half_t*)(ws + (size_t)14 * 1048576);  // 2 MB
  half_t* Qh    = (half_t*)(ws + (size_t)16 * 1048576);  // 8 MB
  half_t* Kh    = (half_t*)(ws + (size_t)24 * 1048576);  // 8 MB
  half_t* Vt    = (half_t*)(ws + (size_t)32 * 1048576);  // 8 MB
  half_t* Hd    = (half_t*)(ws + (size_t)40 * 1048576);  // 8 MB

  cvt_f32_f16<<<(4194304 / 4 + 255) / 256, 256, 0, stream>>>(x, xb, 4194304 / 4);
  cvt_f32_f16<<<(3145728 / 4 + 255) / 256, 256, 0, stream>>>(w_qkv, wqkvb, 3145728 / 4);
  cvt_f32_f16<<<(1048576 / 4 + 255) / 256, 256, 0, stream>>>(w_o, wob, 1048576 / 4);

  qkv_gemm<<<dim3(24, 32), 256, 0, stream>>>(xb, wqkvb, b_qkv, Qh, Kh, Vt);
  attn_kernel<<<dim3(32, 32), 256, 0, stream>>>(Qh, Kh, Vt, Hd);
  out_gemm<<<dim3(8, 32), 256, 0, stream>>>(Hd, wob, b_o, x, out);
}

// Round 2
// 243.380 us; speedup vs baseline: 2.0103x; 2.0103x over previous
//
#include <hip/hip_runtime.h>
#include <hip/hip_bf16.h>
#include <stdint.h>

typedef _Float16 half_t;
typedef _Float16 half4 __attribute__((ext_vector_type(4)));
typedef _Float16 half8 __attribute__((ext_vector_type(8)));
typedef float f32x4 __attribute__((ext_vector_type(4)));

#define SCALE_ 0.03125f   // 1/sqrt(1024)

// async global->LDS, 16B per lane, wave-uniform LDS base + lane*16
#define GLL16(g, l)                                                        \
  __builtin_amdgcn_global_load_lds(                                        \
      (const __attribute__((address_space(1))) void*)(g),                  \
      (__attribute__((address_space(3))) void*)(l), 16, 0, 0)

// ---------------------------------------------------------------- converts
__global__ void cvt_f32_f16(const float* __restrict__ in,
                            half_t* __restrict__ out, int n4) {
  int i = blockIdx.x * blockDim.x + threadIdx.x;
  if (i < n4) {
    float4 v = ((const float4*)in)[i];
    half4 h;
    h[0] = (half_t)v.x; h[1] = (half_t)v.y; h[2] = (half_t)v.z; h[3] = (half_t)v.w;
    ((half4*)out)[i] = h;
  }
}

// ---------------------------------------------------------------- QKV GEMM
__global__ __launch_bounds__(256) void qkv_gemm(
    const half_t* __restrict__ A, const half_t* __restrict__ Bw,
    const float* __restrict__ bias,
    half_t* __restrict__ Qh, half_t* __restrict__ Kh, half_t* __restrict__ Vt) {
  __shared__ __align__(16) half_t As[128 * 32];
  __shared__ __align__(16) half_t Bs[128 * 32];
  const int tid = threadIdx.x;
  const int wave = tid >> 6, lane = tid & 63;
  const int t = lane & 15, g = lane >> 4;
  const int wr = (wave >> 1) * 64, wc = (wave & 1) * 64;
  const int m0 = blockIdx.y * 128, n0 = blockIdx.x * 128;

  f32x4 acc[4][4];
#pragma unroll
  for (int i = 0; i < 4; ++i)
#pragma unroll
    for (int j = 0; j < 4; ++j) acc[i][j] = (f32x4){0.f, 0.f, 0.f, 0.f};

  const int srow = tid >> 2, schunk = (tid & 3) * 8;
  const half_t* aptr = A + (size_t)(m0 + srow) * 1024 + schunk;
  const half_t* bptr = Bw + (size_t)(n0 + srow) * 1024 + schunk;
  char* asb = (char*)As + wave * 1024;
  char* bsb = (char*)Bs + wave * 1024;

  for (int kk = 0; kk < 1024; kk += 32) {
    GLL16(aptr, asb);
    GLL16(aptr + 64 * 1024, asb + 4096);
    GLL16(bptr, bsb);
    GLL16(bptr + 64 * 1024, bsb + 4096);
    aptr += 32; bptr += 32;
    __syncthreads();

    half8 af[4], bf[4];
#pragma unroll
    for (int fm = 0; fm < 4; ++fm)
      af[fm] = *(const half8*)&As[(wr + fm * 16 + t) * 32 + g * 8];
#pragma unroll
    for (int fn = 0; fn < 4; ++fn)
      bf[fn] = *(const half8*)&Bs[(wc + fn * 16 + t) * 32 + g * 8];
#pragma unroll
    for (int fm = 0; fm < 4; ++fm)
#pragma unroll
      for (int fn = 0; fn < 4; ++fn)
        acc[fm][fn] = __builtin_amdgcn_mfma_f32_16x16x32_f16(
            af[fm], bf[fn], acc[fm][fn], 0, 0, 0);
    __syncthreads();
  }

#pragma unroll
  for (int fm = 0; fm < 4; ++fm) {
    const int mb = m0 + wr + fm * 16 + g * 4;
#pragma unroll
    for (int fn = 0; fn < 4; ++fn) {
      const int n = n0 + wc + fn * 16 + t;
      const float bv = bias[n];
      const int sec = n >> 10, nn = n & 1023;
      const int h = nn >> 6, c = nn & 63;
#pragma unroll
      for (int r = 0; r < 4; ++r) {
        const int mm = mb + r;
        const int b = mm >> 11, l = mm & 2047;
        const float v = acc[fm][fn][r] + bv;
        const size_t bh = (size_t)(b * 16 + h);
        if (sec == 0)      Qh[(bh * 2048 + l) * 64 + c] = (half_t)(v * SCALE_);
        else if (sec == 1) Kh[(bh * 2048 + l) * 64 + c] = (half_t)v;
        else               Vt[(bh * 64 + c) * 2048 + l] = (half_t)v;
      }
    }
  }
}

// ---------------------------------------------------------------- attention
// Qh/Kh: [32][2048][64] f16 (Q pre-scaled); Vt: [32][64][2048] f16
// LDS-staged, double-buffered, swizzled (K: cb^=(r&7)<<4; V: mb^=(c&3)<<5)
__global__ __launch_bounds__(256) void attn_kernel(
    const half_t* __restrict__ Qh, const half_t* __restrict__ Kh,
    const half_t* __restrict__ Vt, half_t* __restrict__ Hd) {
  __shared__ __align__(16) half_t Ks[2][64 * 64];
  __shared__ __align__(16) half_t Vs[2][64 * 64];
  const int bh = blockIdx.x;   // 0..31  (b*16+h)
  const int qt = blockIdx.y;   // 0..31  (64 q rows each)
  const int tid = threadIdx.x;
  const int wave = tid >> 6, lane = tid & 63;
  const int t = lane & 15, g = lane >> 4;

  const half_t* Q = Qh + ((size_t)bh * 2048 + qt * 64 + wave * 16) * 64;
  const half_t* Kbase = Kh + (size_t)bh * 2048 * 64;
  const half_t* Vbase = Vt + (size_t)bh * 64 * 2048;

  const half8 q0 = *(const half8*)&Q[t * 64 + g * 8];
  const half8 q1 = *(const half8*)&Q[t * 64 + 32 + g * 8];

  f32x4 o[4];
#pragma unroll
  for (int i = 0; i < 4; ++i) o[i] = (f32x4){0.f, 0.f, 0.f, 0.f};
  float m_run = -1e30f, l_run = 0.f;

  // stage K-tile [64 rows][64 cols] + V-tile [64 c][64 m] for tile at mt.
  // pre-swizzled global source, linear LDS dest (rule #21).
#define STAGE_TILE(bufi, mt_)                                                 \
  {                                                                           \
    char* kb = (char*)Ks[bufi];                                               \
    char* vb = (char*)Vs[bufi];                                               \
    _Pragma("unroll")                                                         \
    for (int is = 0; is < 2; ++is) {                                          \
      const int s = tid + is * 256;                                           \
      const int r = s >> 3, rb = (s & 7) * 16;                                \
      const int kcb = rb ^ ((r & 7) << 4);                                    \
      const int vcb = rb ^ ((r & 3) << 5);                                    \
      GLL16(Kbase + (size_t)((mt_) + r) * 64 + (kcb >> 1),                    \
            kb + (wave * 64 + is * 256) * 16);                                \
      GLL16(Vbase + (size_t)r * 2048 + (mt_) + (vcb >> 1),                    \
            vb + (wave * 64 + is * 256) * 16);                                \
    }                                                                         \
  }

  STAGE_TILE(0, 0);
  __syncthreads();
  int cur = 0;

  for (int it = 0; it < 32; ++it) {
    const int mt = it * 64;
    if (it + 1 < 32) STAGE_TILE(cur ^ 1, mt + 64);

    const char* kbB = (const char*)Ks[cur];
    const char* vbB = (const char*)Vs[cur];

    // S^T = K * Q^T : D[row=m][col=q]
    f32x4 s4[4];
    __builtin_amdgcn_s_setprio(1);
#pragma unroll
    for (int st = 0; st < 4; ++st) {
      const int row = st * 16 + t;
      half8 k0 = *(const half8*)(kbB + row * 128 + ((g * 16) ^ ((t & 7) << 4)));
      half8 k1 = *(const half8*)(kbB + row * 128 + ((64 + g * 16) ^ ((t & 7) << 4)));
      f32x4 a = (f32x4){0.f, 0.f, 0.f, 0.f};
      a = __builtin_amdgcn_mfma_f32_16x16x32_f16(k0, q0, a, 0, 0, 0);
      a = __builtin_amdgcn_mfma_f32_16x16x32_f16(k1, q1, a, 0, 0, 0);
      s4[st] = a;
    }
    __builtin_amdgcn_s_setprio(0);

    float tm = -1e30f;
#pragma unroll
    for (int st = 0; st < 4; ++st)
#pragma unroll
      for (int r = 0; r < 4; ++r) tm = fmaxf(tm, s4[st][r]);
    tm = fmaxf(tm, __shfl_xor(tm, 16));
    tm = fmaxf(tm, __shfl_xor(tm, 32));

    const float mnew = fmaxf(m_run, tm);
    const float corr = __expf(m_run - mnew);
    m_run = mnew;

    float rs = 0.f;
    half4 pf[4];
#pragma unroll
    for (int st = 0; st < 4; ++st)
#pragma unroll
      for (int r = 0; r < 4; ++r) {
        const float p = __expf(s4[st][r] - mnew);
        rs += p;
        pf[st][r] = (half_t)p;
      }
    rs += __shfl_xor(rs, 16);
    rs += __shfl_xor(rs, 32);
    l_run = l_run * corr + rs;

#pragma unroll
    for (int r = 0; r < 4; ++r) {
      const float cv = __shfl(corr, (g << 2) + r);
#pragma unroll
      for (int ct = 0; ct < 4; ++ct) o[ct][r] *= cv;
    }

    // PV: D[row=q][col=c] += P * V
    __builtin_amdgcn_s_setprio(1);
#pragma unroll
    for (int st = 0; st < 4; ++st)
#pragma unroll
      for (int ct = 0; ct < 4; ++ct) {
        const int c = ct * 16 + t;
        half4 vf = *(const half4*)(vbB + c * 128 +
                                   ((st * 32 + g * 8) ^ ((t & 3) << 5)));
        o[ct] = __builtin_amdgcn_mfma_f32_16x16x16f16(pf[st], vf, o[ct], 0, 0, 0);
      }
    __builtin_amdgcn_s_setprio(0);

    __syncthreads();  // drains vmcnt(0): next tile staged; buf safe to swap
    cur ^= 1;
  }

  const int b = bh >> 4, h = bh & 15;
#pragma unroll
  for (int r = 0; r < 4; ++r) {
    const float li = 1.f / __shfl(l_run, (g << 2) + r);
    const size_t row = (size_t)b * 2048 + qt * 64 + wave * 16 + g * 4 + r;
#pragma unroll
    for (int ct = 0; ct < 4; ++ct)
      Hd[row * 1024 + h * 64 + ct * 16 + t] = (half_t)(o[ct][r] * li);
  }
#undef STAGE_TILE
}

// ---------------------------------------------------------------- out GEMM
__global__ __launch_bounds__(256) void out_gemm(
    const half_t* __restrict__ A, const half_t* __restrict__ Bw,
    const float* __restrict__ bias, const float* __restrict__ xres,
    float* __restrict__ out) {
  __shared__ __align__(16) half_t As[128 * 32];
  __shared__ __align__(16) half_t Bs[128 * 32];
  const int tid = threadIdx.x;
  const int wave = tid >> 6, lane = tid & 63;
  const int t = lane & 15, g = lane >> 4;
  const int wr = (wave >> 1) * 64, wc = (wave & 1) * 64;
  const int m0 = blockIdx.y * 128, n0 = blockIdx.x * 128;

  f32x4 acc[4][4];
#pragma unroll
  for (int i = 0; i < 4; ++i)
#pragma unroll
    for (int j = 0; j < 4; ++j) acc[i][j] = (f32x4){0.f, 0.f, 0.f, 0.f};

  const int srow = tid >> 2, schunk = (tid & 3) * 8;
  const half_t* aptr = A + (size_t)(m0 + srow) * 1024 + schunk;
  const half_t* bptr = Bw + (size_t)(n0 + srow) * 1024 + schunk;
  char* asb = (char*)As + wave * 1024;
  char* bsb = (char*)Bs + wave * 1024;

  for (int kk = 0; kk < 1024; kk += 32) {
    GLL16(aptr, asb);
    GLL16(aptr + 64 * 1024, asb + 4096);
    GLL16(bptr, bsb);
    GLL16(bptr + 64 * 1024, bsb + 4096);
    aptr += 32; bptr += 32;
    __syncthreads();

    half8 af[4], bf[4];
#pragma unroll
    for (int fm = 0; fm < 4; ++fm)
      af[fm] = *(const half8*)&As[(wr + fm * 16 + t) * 32 + g * 8];
#pragma unroll
    for (int fn = 0; fn < 4; ++fn)
      bf[fn] = *(const half8*)&Bs[(wc + fn * 16 + t) * 32 + g * 8];
#pragma unroll
    for (int fm = 0; fm < 4; ++fm)
#pragma unroll
      for (int fn = 0; fn < 4; ++fn)
        acc[fm][fn] = __builtin_amdgcn_mfma_f32_16x16x32_f16(
            af[fm], bf[fn], acc[fm][fn], 0, 0, 0);
    __syncthreads();
  }

#pragma unroll
  for (int fm = 0; fm < 4; ++fm) {
    const int mb = m0 + wr + fm * 16 + g * 4;
#pragma unroll
    for (int fn = 0; fn < 4; ++fn) {
      const int n = n0 + wc + fn * 16 + t;
      const float bv = bias[n];
#pragma unroll
      for (int r = 0; r < 4; ++r) {
        const size_t idx = (size_t)(mb + r) * 1024 + n;
        out[idx] = acc[fm][fn][r] + bv + xres[idx];
      }
    }
  }
}

// ---------------------------------------------------------------- launch
extern "C" void kernel_launch(void* const* d_in, const int* in_sizes, int n_in,
                              void* d_out, int out_size, void* d_ws, size_t ws_size,
                              hipStream_t stream) {
  const float* x     = (const float*)d_in[0];
  const float* w_qkv = (const float*)d_in[1];
  const float* b_qkv = (const float*)d_in[2];
  const float* w_o   = (const float*)d_in[3];
  const float* b_o   = (const float*)d_in[4];
  float* out = (float*)d_out;

  char* ws = (char*)d_ws;
  half_t* xb    = (half_t*)(ws + 0);                     // 8 MB
  half_t* wqkvb = (half_t*)(ws + (size_t)8  * 1048576);  // 6 MB
  half_t* wob   = (half_t*)(ws + (size_t)14 * 1048576);  // 2 MB
  half_t* Qh    = (half_t*)(ws + (size_t)16 * 1048576);  // 8 MB
  half_t* Kh    = (half_t*)(ws + (size_t)24 * 1048576);  // 8 MB
  half_t* Vt    = (half_t*)(ws + (size_t)32 * 1048576);  // 8 MB
  half_t* Hd    = (half_t*)(ws + (size_t)40 * 1048576);  // 8 MB

  cvt_f32_f16<<<(4194304 / 4 + 255) / 256, 256, 0, stream>>>(x, xb, 4194304 / 4);
  cvt_f32_f16<<<(3145728 / 4 + 255) / 256, 256, 0, stream>>>(w_qkv, wqkvb, 3145728 / 4);
  cvt_f32_f16<<<(1048576 / 4 + 255) / 256, 256, 0, stream>>>(w_o, wob, 1048576 / 4);

  qkv_gemm<<<dim3(24, 32), 256, 0, stream>>>(xb, wqkvb, b_qkv, Qh, Kh, Vt);
  attn_kernel<<<dim3(32, 32), 256, 0, stream>>>(Qh, Kh, Vt, Hd);
  out_gemm<<<dim3(8, 32), 256, 0, stream>>>(Hd, wob, b_o, x, out);
}

// Round 4
// 218.912 us; speedup vs baseline: 2.2350x; 1.1118x over previous
//
#include <hip/hip_runtime.h>
#include <hip/hip_bf16.h>
#include <stdint.h>

typedef _Float16 half_t;
typedef _Float16 half4 __attribute__((ext_vector_type(4)));
typedef _Float16 half8 __attribute__((ext_vector_type(8)));
typedef float f32x4 __attribute__((ext_vector_type(4)));

// Q prescale: 1/sqrt(1024) * log2(e)  -> softmax computed in exp2 space
#define SCALE2_ 0.045084220f

#if __has_builtin(__builtin_amdgcn_exp2f)
#define EXP2F(x) __builtin_amdgcn_exp2f(x)
#else
#define EXP2F(x) exp2f(x)
#endif

// async global->LDS, 16B per lane, wave-uniform LDS base + lane*16
#define GLL16(g, l)                                                        \
  __builtin_amdgcn_global_load_lds(                                        \
      (const __attribute__((address_space(1))) void*)(g),                  \
      (__attribute__((address_space(3))) void*)(l), 16, 0, 0)

// ---------------------------------------------------------------- converts
// all three f32->f16 conversions in one kernel (index ranges in float4 units)
__global__ void cvt_all(const float* __restrict__ x,
                        const float* __restrict__ wqkv,
                        const float* __restrict__ wo,
                        half_t* __restrict__ xb,
                        half_t* __restrict__ wqkvb,
                        half_t* __restrict__ wob) {
  int i = blockIdx.x * blockDim.x + threadIdx.x;
  const float* src; half_t* dst; int off;
  if (i < 1048576)       { src = x;    dst = xb;    off = i; }
  else if (i < 1835008)  { src = wqkv; dst = wqkvb; off = i - 1048576; }
  else                   { src = wo;   dst = wob;   off = i - 1835008; }
  float4 v = ((const float4*)src)[off];
  half4 h;
  h[0] = (half_t)v.x; h[1] = (half_t)v.y; h[2] = (half_t)v.z; h[3] = (half_t)v.w;
  ((half4*)dst)[off] = h;
}

// ---------------------------------------------------------------- QKV GEMM
__global__ __launch_bounds__(256) void qkv_gemm(
    const half_t* __restrict__ A, const half_t* __restrict__ Bw,
    const float* __restrict__ bias,
    half_t* __restrict__ Qh, half_t* __restrict__ Kh, half_t* __restrict__ Vt) {
  __shared__ __align__(16) half_t As[128 * 32];
  __shared__ __align__(16) half_t Bs[128 * 32];
  const int tid = threadIdx.x;
  const int wave = tid >> 6, lane = tid & 63;
  const int t = lane & 15, g = lane >> 4;
  const int wr = (wave >> 1) * 64, wc = (wave & 1) * 64;
  const int m0 = blockIdx.y * 128, n0 = blockIdx.x * 128;

  f32x4 acc[4][4];
#pragma unroll
  for (int i = 0; i < 4; ++i)
#pragma unroll
    for (int j = 0; j < 4; ++j) acc[i][j] = (f32x4){0.f, 0.f, 0.f, 0.f};

  const int srow = tid >> 2, schunk = (tid & 3) * 8;
  const half_t* aptr = A + (size_t)(m0 + srow) * 1024 + schunk;
  const half_t* bptr = Bw + (size_t)(n0 + srow) * 1024 + schunk;
  char* asb = (char*)As + wave * 1024;
  char* bsb = (char*)Bs + wave * 1024;

  for (int kk = 0; kk < 1024; kk += 32) {
    GLL16(aptr, asb);
    GLL16(aptr + 64 * 1024, asb + 4096);
    GLL16(bptr, bsb);
    GLL16(bptr + 64 * 1024, bsb + 4096);
    aptr += 32; bptr += 32;
    __syncthreads();

    half8 af[4], bf[4];
#pragma unroll
    for (int fm = 0; fm < 4; ++fm)
      af[fm] = *(const half8*)&As[(wr + fm * 16 + t) * 32 + g * 8];
#pragma unroll
    for (int fn = 0; fn < 4; ++fn)
      bf[fn] = *(const half8*)&Bs[(wc + fn * 16 + t) * 32 + g * 8];
#pragma unroll
    for (int fm = 0; fm < 4; ++fm)
#pragma unroll
      for (int fn = 0; fn < 4; ++fn)
        acc[fm][fn] = __builtin_amdgcn_mfma_f32_16x16x32_f16(
            af[fm], bf[fn], acc[fm][fn], 0, 0, 0);
    __syncthreads();
  }

#pragma unroll
  for (int fm = 0; fm < 4; ++fm) {
    const int mb = m0 + wr + fm * 16 + g * 4;
#pragma unroll
    for (int fn = 0; fn < 4; ++fn) {
      const int n = n0 + wc + fn * 16 + t;
      const float bv = bias[n];
      const int sec = n >> 10, nn = n & 1023;
      const int h = nn >> 6, c = nn & 63;
#pragma unroll
      for (int r = 0; r < 4; ++r) {
        const int mm = mb + r;
        const int b = mm >> 11, l = mm & 2047;
        const float v = acc[fm][fn][r] + bv;
        const size_t bh = (size_t)(b * 16 + h);
        if (sec == 0)      Qh[(bh * 2048 + l) * 64 + c] = (half_t)(v * SCALE2_);
        else if (sec == 1) Kh[(bh * 2048 + l) * 64 + c] = (half_t)v;
        else {
          // permute column within its 64-tile: swap (st,g) 2-bit fields so
          // attention can read PV fragments as contiguous b128 pairs
          const int lp = (l & ~63) |
                         (((l >> 2) & 3) * 16 + ((l >> 4) & 3) * 4 + (l & 3));
          Vt[(bh * 64 + c) * 2048 + lp] = (half_t)v;
        }
      }
    }
  }
}

// ---------------------------------------------------------------- attention
// Qh/Kh: [32][2048][64] f16 (Q pre-scaled by SCALE2_); Vt: [32][64][2048] f16
// (V columns permuted per 64-tile). LDS double-buffered, row-XOR swizzled.
__global__ __launch_bounds__(256) void attn_kernel(
    const half_t* __restrict__ Qh, const half_t* __restrict__ Kh,
    const half_t* __restrict__ Vt, half_t* __restrict__ Hd) {
  __shared__ __align__(16) char lds_raw[2][2][8192];  // [buf][K=0/V=1][8KB]
  const int bh = blockIdx.x;   // 0..31  (b*16+h)
  const int qt = blockIdx.y;   // 0..31  (64 q rows each)
  const int tid = threadIdx.x;
  const int wave = tid >> 6, lane = tid & 63;
  const int t = lane & 15, g = lane >> 4;

  const half_t* Q = Qh + ((size_t)bh * 2048 + qt * 64 + wave * 16) * 64;
  const half_t* Kbase = Kh + (size_t)bh * 2048 * 64;
  const half_t* Vbase = Vt + (size_t)bh * 64 * 2048;

  const half8 q0 = *(const half8*)&Q[t * 64 + g * 8];
  const half8 q1 = *(const half8*)&Q[t * 64 + 32 + g * 8];

  // hoisted, buffer-relative LDS read byte offsets (rest folds into imm)
  const int swz = (t & 7) << 4;
  const int vk0 = t * 128 + ((g * 16) ^ swz);
  const int vk1 = t * 128 + ((64 + g * 16) ^ swz);
  const int vv0 = t * 128 + ((g * 32) ^ swz);
  const int vv1 = t * 128 + ((g * 32 + 16) ^ swz);

  f32x4 o[4];
#pragma unroll
  for (int i = 0; i < 4; ++i) o[i] = (f32x4){0.f, 0.f, 0.f, 0.f};
  float m_run = -1e30f, l_run = 0.f;

#define STAGE_TILE(bufi, mt_)                                                 \
  {                                                                           \
    char* kb_ = lds_raw[bufi][0];                                             \
    char* vb_ = lds_raw[bufi][1];                                             \
    _Pragma("unroll")                                                         \
    for (int is = 0; is < 2; ++is) {                                          \
      const int s = tid + is * 256;                                           \
      const int r = s >> 3, rb = (s & 7) * 16;                                \
      const int cb = rb ^ ((r & 7) << 4);                                     \
      GLL16(Kbase + (size_t)((mt_) + r) * 64 + (cb >> 1),                     \
            kb_ + (wave * 64 + is * 256) * 16);                               \
      GLL16(Vbase + (size_t)r * 2048 + (mt_) + (cb >> 1),                     \
            vb_ + (wave * 64 + is * 256) * 16);                               \
    }                                                                         \
  }

  STAGE_TILE(0, 0);
  __syncthreads();

  for (int it = 0; it < 32; ++it) {
    const int mt = it * 64;
    const int cur = it & 1;
    if (it + 1 < 32) STAGE_TILE(cur ^ 1, mt + 64);

    const char* kb = lds_raw[cur][0];
    const char* vb = lds_raw[cur][1];

    // S^T = K * Q^T : D[row=m][col=q]; lane holds S[q=t][m=st*16+g*4+r]
    f32x4 s4[4];
    __builtin_amdgcn_s_setprio(1);
#pragma unroll
    for (int st = 0; st < 4; ++st) {
      half8 k0 = *(const half8*)(kb + vk0 + st * 2048);
      half8 k1 = *(const half8*)(kb + vk1 + st * 2048);
      f32x4 a = (f32x4){0.f, 0.f, 0.f, 0.f};
      a = __builtin_amdgcn_mfma_f32_16x16x32_f16(k0, q0, a, 0, 0, 0);
      a = __builtin_amdgcn_mfma_f32_16x16x32_f16(k1, q1, a, 0, 0, 0);
      s4[st] = a;
    }
    __builtin_amdgcn_s_setprio(0);

    // tile max per q-column
    float tm = fmaxf(fmaxf(fmaxf(s4[0][0], s4[0][1]), fmaxf(s4[0][2], s4[0][3])),
                     fmaxf(fmaxf(s4[1][0], s4[1][1]), fmaxf(s4[1][2], s4[1][3])));
    tm = fmaxf(tm,
         fmaxf(fmaxf(fmaxf(s4[2][0], s4[2][1]), fmaxf(s4[2][2], s4[2][3])),
               fmaxf(fmaxf(s4[3][0], s4[3][1]), fmaxf(s4[3][2], s4[3][3]))));
    tm = fmaxf(tm, __shfl_xor(tm, 16));
    tm = fmaxf(tm, __shfl_xor(tm, 32));

    // defer-max: only rescale when some q-row grew past m_run + 10 (log2)
    if (!__all(tm <= m_run + 10.f)) {
      const float mnew = fmaxf(m_run, tm);
      const float corr = EXP2F(m_run - mnew);
      m_run = mnew;
      l_run *= corr;
#pragma unroll
      for (int r = 0; r < 4; ++r) {
        const float cv = __shfl(corr, (g << 2) + r);
#pragma unroll
        for (int ct = 0; ct < 4; ++ct) o[ct][r] *= cv;
      }
    }

    float rs = 0.f;
    half4 pf[4];
#pragma unroll
    for (int st = 0; st < 4; ++st) {
      const float p0 = EXP2F(s4[st][0] - m_run);
      const float p1 = EXP2F(s4[st][1] - m_run);
      const float p2 = EXP2F(s4[st][2] - m_run);
      const float p3 = EXP2F(s4[st][3] - m_run);
      rs += (p0 + p1) + (p2 + p3);
      pf[st][0] = (half_t)p0; pf[st][1] = (half_t)p1;
      pf[st][2] = (half_t)p2; pf[st][3] = (half_t)p3;
    }
    rs += __shfl_xor(rs, 16);
    rs += __shfl_xor(rs, 32);
    l_run += rs;

    // PV: D[row=q][col=c] += P * V ; b128 read yields fragments st,st+1
    __builtin_amdgcn_s_setprio(1);
#pragma unroll
    for (int sthalf = 0; sthalf < 2; ++sthalf) {
      const int voff = sthalf ? vv1 : vv0;
#pragma unroll
      for (int ct = 0; ct < 4; ++ct) {
        half8 vv = *(const half8*)(vb + voff + ct * 2048);
        half4 vlo = {vv[0], vv[1], vv[2], vv[3]};
        half4 vhi = {vv[4], vv[5], vv[6], vv[7]};
        o[ct] = __builtin_amdgcn_mfma_f32_16x16x16f16(pf[2 * sthalf], vlo,
                                                      o[ct], 0, 0, 0);
        o[ct] = __builtin_amdgcn_mfma_f32_16x16x16f16(pf[2 * sthalf + 1], vhi,
                                                      o[ct], 0, 0, 0);
      }
    }
    __builtin_amdgcn_s_setprio(0);

    __syncthreads();  // next tile staged (drains vmcnt); safe to swap buffers
  }

  const int b = bh >> 4, h = bh & 15;
#pragma unroll
  for (int r = 0; r < 4; ++r) {
    const float li = 1.f / __shfl(l_run, (g << 2) + r);
    const size_t row = (size_t)b * 2048 + qt * 64 + wave * 16 + g * 4 + r;
#pragma unroll
    for (int ct = 0; ct < 4; ++ct)
      Hd[row * 1024 + h * 64 + ct * 16 + t] = (half_t)(o[ct][r] * li);
  }
#undef STAGE_TILE
}

// ---------------------------------------------------------------- out GEMM
__global__ __launch_bounds__(256) void out_gemm(
    const half_t* __restrict__ A, const half_t* __restrict__ Bw,
    const float* __restrict__ bias, const float* __restrict__ xres,
    float* __restrict__ out) {
  __shared__ __align__(16) half_t As[128 * 32];
  __shared__ __align__(16) half_t Bs[128 * 32];
  const int tid = threadIdx.x;
  const int wave = tid >> 6, lane = tid & 63;
  const int t = lane & 15, g = lane >> 4;
  const int wr = (wave >> 1) * 64, wc = (wave & 1) * 64;
  const int m0 = blockIdx.y * 128, n0 = blockIdx.x * 128;

  f32x4 acc[4][4];
#pragma unroll
  for (int i = 0; i < 4; ++i)
#pragma unroll
    for (int j = 0; j < 4; ++j) acc[i][j] = (f32x4){0.f, 0.f, 0.f, 0.f};

  const int srow = tid >> 2, schunk = (tid & 3) * 8;
  const half_t* aptr = A + (size_t)(m0 + srow) * 1024 + schunk;
  const half_t* bptr = Bw + (size_t)(n0 + srow) * 1024 + schunk;
  char* asb = (char*)As + wave * 1024;
  char* bsb = (char*)Bs + wave * 1024;

  for (int kk = 0; kk < 1024; kk += 32) {
    GLL16(aptr, asb);
    GLL16(aptr + 64 * 1024, asb + 4096);
    GLL16(bptr, bsb);
    GLL16(bptr + 64 * 1024, bsb + 4096);
    aptr += 32; bptr += 32;
    __syncthreads();

    half8 af[4], bf[4];
#pragma unroll
    for (int fm = 0; fm < 4; ++fm)
      af[fm] = *(const half8*)&As[(wr + fm * 16 + t) * 32 + g * 8];
#pragma unroll
    for (int fn = 0; fn < 4; ++fn)
      bf[fn] = *(const half8*)&Bs[(wc + fn * 16 + t) * 32 + g * 8];
#pragma unroll
    for (int fm = 0; fm < 4; ++fm)
#pragma unroll
      for (int fn = 0; fn < 4; ++fn)
        acc[fm][fn] = __builtin_amdgcn_mfma_f32_16x16x32_f16(
            af[fm], bf[fn], acc[fm][fn], 0, 0, 0);
    __syncthreads();
  }

#pragma unroll
  for (int fm = 0; fm < 4; ++fm) {
    const int mb = m0 + wr + fm * 16 + g * 4;
#pragma unroll
    for (int fn = 0; fn < 4; ++fn) {
      const int n = n0 + wc + fn * 16 + t;
      const float bv = bias[n];
#pragma unroll
      for (int r = 0; r < 4; ++r) {
        const size_t idx = (size_t)(mb + r) * 1024 + n;
        out[idx] = acc[fm][fn][r] + bv + xres[idx];
      }
    }
  }
}

// ---------------------------------------------------------------- launch
extern "C" void kernel_launch(void* const* d_in, const int* in_sizes, int n_in,
                              void* d_out, int out_size, void* d_ws, size_t ws_size,
                              hipStream_t stream) {
  const float* x     = (const float*)d_in[0];
  const float* w_qkv = (const float*)d_in[1];
  const float* b_qkv = (const float*)d_in[2];
  const float* w_o   = (const float*)d_in[3];
  const float* b_o   = (const float*)d_in[4];
  float* out = (float*)d_out;

  char* ws = (char*)d_ws;
  half_t* xb    = (half_t*)(ws + 0);                     // 8 MB
  half_t* wqkvb = (half_t*)(ws + (size_t)8  * 1048576);  // 6 MB
  half_t* wob   = (half_t*)(ws + (size_t)14 * 1048576);  // 2 MB
  half_t* Qh    = (half_t*)(ws + (size_t)16 * 1048576);  // 8 MB
  half_t* Kh    = (half_t*)(ws + (size_t)24 * 1048576);  // 8 MB
  half_t* Vt    = (half_t*)(ws + (size_t)32 * 1048576);  // 8 MB
  half_t* Hd    = (half_t*)(ws + (size_t)40 * 1048576);  // 8 MB

  cvt_all<<<8192, 256, 0, stream>>>(x, w_qkv, w_o, xb, wqkvb, wob);
  qkv_gemm<<<dim3(24, 32), 256, 0, stream>>>(xb, wqkvb, b_qkv, Qh, Kh, Vt);
  attn_kernel<<<dim3(32, 32), 256, 0, stream>>>(Qh, Kh, Vt, Hd);
  out_gemm<<<dim3(8, 32), 256, 0, stream>>>(Hd, wob, b_o, x, out);
}

// Round 5
// 204.367 us; speedup vs baseline: 2.3941x; 1.0712x over previous
//
#include <hip/hip_runtime.h>
#include <hip/hip_bf16.h>
#include <stdint.h>

typedef _Float16 half_t;
typedef _Float16 half4 __attribute__((ext_vector_type(4)));
typedef _Float16 half8 __attribute__((ext_vector_type(8)));
typedef float f32x4 __attribute__((ext_vector_type(4)));

// Q prescale: 1/sqrt(1024) * log2(e)  -> softmax computed in exp2 space
#define SCALE2_ 0.045084220f

#if __has_builtin(__builtin_amdgcn_exp2f)
#define EXP2F(x) __builtin_amdgcn_exp2f(x)
#else
#define EXP2F(x) exp2f(x)
#endif

#define GLL16(g, l)                                                        \
  __builtin_amdgcn_global_load_lds(                                        \
      (const __attribute__((address_space(1))) void*)(g),                  \
      (__attribute__((address_space(3))) void*)(l), 16, 0, 0)

// ---------------------------------------------------------------- converts
__global__ void cvt_all(const float* __restrict__ x,
                        const float* __restrict__ wqkv,
                        const float* __restrict__ wo,
                        half_t* __restrict__ xb,
                        half_t* __restrict__ wqkvb,
                        half_t* __restrict__ wob) {
  int i = blockIdx.x * blockDim.x + threadIdx.x;
  const float* src; half_t* dst; int off;
  if (i < 1048576)       { src = x;    dst = xb;    off = i; }
  else if (i < 1835008)  { src = wqkv; dst = wqkvb; off = i - 1048576; }
  else                   { src = wo;   dst = wob;   off = i - 1835008; }
  float4 v = ((const float4*)src)[off];
  half4 h;
  h[0] = (half_t)v.x; h[1] = (half_t)v.y; h[2] = (half_t)v.z; h[3] = (half_t)v.w;
  ((half4*)dst)[off] = h;
}

// ---------------------------------------------------------------- QKV GEMM
// 128x128 tile, BK=64, XOR-swizzled LDS (rows 128B span all 32 banks).
__global__ __launch_bounds__(256) void qkv_gemm(
    const half_t* __restrict__ A, const half_t* __restrict__ Bw,
    const float* __restrict__ bias,
    half_t* __restrict__ Qh, half_t* __restrict__ Kh, half_t* __restrict__ Vt) {
  __shared__ __align__(16) half_t As[128 * 64];
  __shared__ __align__(16) half_t Bs[128 * 64];
  const int tid = threadIdx.x;
  const int wave = tid >> 6, lane = tid & 63;
  const int t = lane & 15, g = lane >> 4;
  const int wr = (wave >> 1) * 64, wc = (wave & 1) * 64;
  const int m0 = blockIdx.y * 128, n0 = blockIdx.x * 128;

  f32x4 acc[4][4];
#pragma unroll
  for (int i = 0; i < 4; ++i)
#pragma unroll
    for (int j = 0; j < 4; ++j) acc[i][j] = (f32x4){0.f, 0.f, 0.f, 0.f};

  // staging: chunk s = tid + is*256; row = s>>3; col byte = ((s&7)*16) ^ ((row&7)<<4)
  const int r0 = tid >> 3;                                  // 0..31
  const int colb = ((tid & 7) * 16) ^ ((r0 & 7) << 4);      // invariant per is
  const half_t* aptr = A + (size_t)(m0 + r0) * 1024 + (colb >> 1);
  const half_t* bptr = Bw + (size_t)(n0 + r0) * 1024 + (colb >> 1);
  const int swz = (t & 7) << 4;

  for (int kk = 0; kk < 16; ++kk) {
#pragma unroll
    for (int is = 0; is < 4; ++is) {
      GLL16(aptr + (size_t)is * 32 * 1024, (char*)As + wave * 1024 + is * 4096);
      GLL16(bptr + (size_t)is * 32 * 1024, (char*)Bs + wave * 1024 + is * 4096);
    }
    aptr += 64; bptr += 64;
    __syncthreads();

#pragma unroll
    for (int h = 0; h < 2; ++h) {
      half8 af[4], bf[4];
#pragma unroll
      for (int fm = 0; fm < 4; ++fm)
        af[fm] = *(const half8*)((const char*)As + (wr + fm * 16 + t) * 128 +
                                 ((h * 64 + g * 16) ^ swz));
#pragma unroll
      for (int fn = 0; fn < 4; ++fn)
        bf[fn] = *(const half8*)((const char*)Bs + (wc + fn * 16 + t) * 128 +
                                 ((h * 64 + g * 16) ^ swz));
#pragma unroll
      for (int fm = 0; fm < 4; ++fm)
#pragma unroll
        for (int fn = 0; fn < 4; ++fn)
          acc[fm][fn] = __builtin_amdgcn_mfma_f32_16x16x32_f16(
              af[fm], bf[fn], acc[fm][fn], 0, 0, 0);
    }
    __syncthreads();
  }

#pragma unroll
  for (int fm = 0; fm < 4; ++fm) {
    const int mb = m0 + wr + fm * 16 + g * 4;
#pragma unroll
    for (int fn = 0; fn < 4; ++fn) {
      const int n = n0 + wc + fn * 16 + t;
      const float bv = bias[n];
      const int sec = n >> 10, nn = n & 1023;
      const int h = nn >> 6, c = nn & 63;
#pragma unroll
      for (int r = 0; r < 4; ++r) {
        const int mm = mb + r;
        const int b = mm >> 11, l = mm & 2047;
        const float v = acc[fm][fn][r] + bv;
        const size_t bh = (size_t)(b * 16 + h);
        if (sec == 0)      Qh[(bh * 2048 + l) * 64 + c] = (half_t)(v * SCALE2_);
        else if (sec == 1) Kh[(bh * 2048 + l) * 64 + c] = (half_t)v;
        else {
          // permute column within its 64-tile so PV reads are contiguous b128
          const int lp = (l & ~63) |
                         (((l >> 2) & 3) * 16 + ((l >> 4) & 3) * 4 + (l & 3));
          Vt[(bh * 64 + c) * 2048 + lp] = (half_t)v;
        }
      }
    }
  }
}

// ---------------------------------------------------------------- attention
// 8 waves/block, 128 q-rows/block; K/V LDS double-buffered, XOR-swizzled.
__global__ __launch_bounds__(512) void attn_kernel(
    const half_t* __restrict__ Qh, const half_t* __restrict__ Kh,
    const half_t* __restrict__ Vt, half_t* __restrict__ Hd) {
  __shared__ __align__(16) char lds_raw[2][2][8192];  // [buf][K=0/V=1][8KB]
  const int bh = blockIdx.x;   // 0..31  (b*16+h)
  const int qt = blockIdx.y;   // 0..15  (128 q rows each)
  const int tid = threadIdx.x;
  const int wave = tid >> 6, lane = tid & 63;
  const int t = lane & 15, g = lane >> 4;

  const half_t* Q = Qh + ((size_t)bh * 2048 + qt * 128 + wave * 16) * 64;
  const half8 q0 = *(const half8*)&Q[t * 64 + g * 8];
  const half8 q1 = *(const half8*)&Q[t * 64 + 32 + g * 8];

  // staging: 512 chunks per tile, 1 K + 1 V per thread, pointer-incremented
  const int r0 = tid >> 3;                                   // 0..63
  const int colb = ((tid & 7) * 16) ^ ((r0 & 7) << 4);
  const half_t* kptr = Kh + (size_t)bh * 2048 * 64 + (size_t)r0 * 64 + (colb >> 1);
  const half_t* vptr = Vt + (size_t)bh * 64 * 2048 + (size_t)r0 * 2048 + (colb >> 1);

  // hoisted LDS read byte offsets
  const int swz = (t & 7) << 4;
  const int vk0 = t * 128 + ((g * 16) ^ swz);
  const int vk1 = t * 128 + ((64 + g * 16) ^ swz);
  const int vv0 = t * 128 + ((g * 32) ^ swz);
  const int vv1 = t * 128 + ((g * 32 + 16) ^ swz);

  f32x4 o[4];
#pragma unroll
  for (int i = 0; i < 4; ++i) o[i] = (f32x4){0.f, 0.f, 0.f, 0.f};
  float m_run = -1e30f, l_run = 0.f;

#define STG(bufi)                                                \
  {                                                              \
    GLL16(kptr, (char*)lds_raw[bufi][0] + wave * 1024);          \
    GLL16(vptr, (char*)lds_raw[bufi][1] + wave * 1024);          \
    kptr += 4096; vptr += 64;                                    \
  }

  STG(0);
  __syncthreads();

  for (int it = 0; it < 32; ++it) {
    const int cur = it & 1;
    if (it + 1 < 32) STG(cur ^ 1);

    const char* kb = lds_raw[cur][0];
    const char* vb = lds_raw[cur][1];

    // S^T = K * Q^T : lane holds S[q=t][m = st*16 + g*4 + r]
    f32x4 s4[4];
    __builtin_amdgcn_s_setprio(1);
#pragma unroll
    for (int st = 0; st < 4; ++st) {
      half8 k0 = *(const half8*)(kb + vk0 + st * 2048);
      half8 k1 = *(const half8*)(kb + vk1 + st * 2048);
      f32x4 a = (f32x4){0.f, 0.f, 0.f, 0.f};
      a = __builtin_amdgcn_mfma_f32_16x16x32_f16(k0, q0, a, 0, 0, 0);
      a = __builtin_amdgcn_mfma_f32_16x16x32_f16(k1, q1, a, 0, 0, 0);
      s4[st] = a;
    }
    __builtin_amdgcn_s_setprio(0);

    // tile max per q-column: max3-friendly triples (16 values)
    float a0 = fmaxf(fmaxf(s4[0][0], s4[0][1]), s4[0][2]);
    float a1 = fmaxf(fmaxf(s4[0][3], s4[1][0]), s4[1][1]);
    float a2 = fmaxf(fmaxf(s4[1][2], s4[1][3]), s4[2][0]);
    float a3 = fmaxf(fmaxf(s4[2][1], s4[2][2]), s4[2][3]);
    float a4 = fmaxf(fmaxf(s4[3][0], s4[3][1]), s4[3][2]);
    float tm = fmaxf(fmaxf(fmaxf(a0, a1), a2), fmaxf(fmaxf(a3, a4), s4[3][3]));
    tm = fmaxf(tm, __shfl_xor(tm, 16));
    tm = fmaxf(tm, __shfl_xor(tm, 32));

    // defer-max: rescale only when some q-row grew past m_run + 10 (log2)
    if (!__all(tm <= m_run + 10.f)) {
      const float mnew = fmaxf(m_run, tm);
      const float corr = EXP2F(m_run - mnew);
      m_run = mnew;
      l_run *= corr;
#pragma unroll
      for (int r = 0; r < 4; ++r) {
        const float cv = __shfl(corr, (g << 2) + r);
#pragma unroll
        for (int ct = 0; ct < 4; ++ct) o[ct][r] *= cv;
      }
    }

    float rs = 0.f;
    half4 pf[4];
#pragma unroll
    for (int st = 0; st < 4; ++st) {
      const float p0 = EXP2F(s4[st][0] - m_run);
      const float p1 = EXP2F(s4[st][1] - m_run);
      const float p2 = EXP2F(s4[st][2] - m_run);
      const float p3 = EXP2F(s4[st][3] - m_run);
      rs += (p0 + p1) + (p2 + p3);
      pf[st][0] = (half_t)p0; pf[st][1] = (half_t)p1;
      pf[st][2] = (half_t)p2; pf[st][3] = (half_t)p3;
    }
    rs += __shfl_xor(rs, 16);
    rs += __shfl_xor(rs, 32);
    l_run += rs;

    // PV: D[row=q][col=c] += P * V
    __builtin_amdgcn_s_setprio(1);
#pragma unroll
    for (int sthalf = 0; sthalf < 2; ++sthalf) {
      const int voff = sthalf ? vv1 : vv0;
#pragma unroll
      for (int ct = 0; ct < 4; ++ct) {
        half8 vv = *(const half8*)(vb + voff + ct * 2048);
        half4 vlo = {vv[0], vv[1], vv[2], vv[3]};
        half4 vhi = {vv[4], vv[5], vv[6], vv[7]};
        o[ct] = __builtin_amdgcn_mfma_f32_16x16x16f16(pf[2 * sthalf], vlo,
                                                      o[ct], 0, 0, 0);
        o[ct] = __builtin_amdgcn_mfma_f32_16x16x16f16(pf[2 * sthalf + 1], vhi,
                                                      o[ct], 0, 0, 0);
      }
    }
    __builtin_amdgcn_s_setprio(0);

    __syncthreads();  // next tile staged (drains vmcnt); safe to swap buffers
  }

  const int b = bh >> 4, h = bh & 15;
#pragma unroll
  for (int r = 0; r < 4; ++r) {
    const float li = 1.f / __shfl(l_run, (g << 2) + r);
    const size_t row = (size_t)b * 2048 + qt * 128 + wave * 16 + g * 4 + r;
#pragma unroll
    for (int ct = 0; ct < 4; ++ct)
      Hd[row * 1024 + h * 64 + ct * 16 + t] = (half_t)(o[ct][r] * li);
  }
#undef STG
}

// ---------------------------------------------------------------- out GEMM
// 64x128 tile, BK=64, XOR-swizzled; grid (8,64)=512 blocks (2/CU).
__global__ __launch_bounds__(256) void out_gemm(
    const half_t* __restrict__ A, const half_t* __restrict__ Bw,
    const float* __restrict__ bias, const float* __restrict__ xres,
    float* __restrict__ out) {
  __shared__ __align__(16) half_t As[64 * 64];
  __shared__ __align__(16) half_t Bs[128 * 64];
  const int tid = threadIdx.x;
  const int wave = tid >> 6, lane = tid & 63;
  const int t = lane & 15, g = lane >> 4;
  const int wr = (wave >> 1) * 32, wc = (wave & 1) * 64;
  const int m0 = blockIdx.y * 64, n0 = blockIdx.x * 128;

  f32x4 acc[2][4];
#pragma unroll
  for (int i = 0; i < 2; ++i)
#pragma unroll
    for (int j = 0; j < 4; ++j) acc[i][j] = (f32x4){0.f, 0.f, 0.f, 0.f};

  const int r0 = tid >> 3;
  const int colb = ((tid & 7) * 16) ^ ((r0 & 7) << 4);
  const half_t* aptr = A + (size_t)(m0 + r0) * 1024 + (colb >> 1);
  const half_t* bptr = Bw + (size_t)(n0 + r0) * 1024 + (colb >> 1);
  const int swz = (t & 7) << 4;

  for (int kk = 0; kk < 16; ++kk) {
#pragma unroll
    for (int is = 0; is < 2; ++is)
      GLL16(aptr + (size_t)is * 32 * 1024, (char*)As + wave * 1024 + is * 4096);
#pragma unroll
    for (int is = 0; is < 4; ++is)
      GLL16(bptr + (size_t)is * 32 * 1024, (char*)Bs + wave * 1024 + is * 4096);
    aptr += 64; bptr += 64;
    __syncthreads();

#pragma unroll
    for (int h = 0; h < 2; ++h) {
      half8 af[2], bf[4];
#pragma unroll
      for (int fm = 0; fm < 2; ++fm)
        af[fm] = *(const half8*)((const char*)As + (wr + fm * 16 + t) * 128 +
                                 ((h * 64 + g * 16) ^ swz));
#pragma unroll
      for (int fn = 0; fn < 4; ++fn)
        bf[fn] = *(const half8*)((const char*)Bs + (wc + fn * 16 + t) * 128 +
                                 ((h * 64 + g * 16) ^ swz));
#pragma unroll
      for (int fm = 0; fm < 2; ++fm)
#pragma unroll
        for (int fn = 0; fn < 4; ++fn)
          acc[fm][fn] = __builtin_amdgcn_mfma_f32_16x16x32_f16(
              af[fm], bf[fn], acc[fm][fn], 0, 0, 0);
    }
    __syncthreads();
  }

#pragma unroll
  for (int fm = 0; fm < 2; ++fm) {
    const int mb = m0 + wr + fm * 16 + g * 4;
#pragma unroll
    for (int fn = 0; fn < 4; ++fn) {
      const int n = n0 + wc + fn * 16 + t;
      const float bv = bias[n];
#pragma unroll
      for (int r = 0; r < 4; ++r) {
        const size_t idx = (size_t)(mb + r) * 1024 + n;
        out[idx] = acc[fm][fn][r] + bv + xres[idx];
      }
    }
  }
}

// ---------------------------------------------------------------- launch
extern "C" void kernel_launch(void* const* d_in, const int* in_sizes, int n_in,
                              void* d_out, int out_size, void* d_ws, size_t ws_size,
                              hipStream_t stream) {
  const float* x     = (const float*)d_in[0];
  const float* w_qkv = (const float*)d_in[1];
  const float* b_qkv = (const float*)d_in[2];
  const float* w_o   = (const float*)d_in[3];
  const float* b_o   = (const float*)d_in[4];
  float* out = (float*)d_out;

  char* ws = (char*)d_ws;
  half_t* xb    = (half_t*)(ws + 0);                     // 8 MB
  half_t* wqkvb = (half_t*)(ws + (size_t)8  * 1048576);  // 6 MB
  half_t* wob   = (half_t*)(ws + (size_t)14 * 1048576);  // 2 MB
  half_t* Qh    = (half_t*)(ws + (size_t)16 * 1048576);  // 8 MB
  half_t* Kh    = (half_t*)(ws + (size_t)24 * 1048576);  // 8 MB
  half_t* Vt    = (half_t*)(ws + (size_t)32 * 1048576);  // 8 MB
  half_t* Hd    = (half_t*)(ws + (size_t)40 * 1048576);  // 8 MB

  cvt_all<<<8192, 256, 0, stream>>>(x, w_qkv, w_o, xb, wqkvb, wob);
  qkv_gemm<<<dim3(24, 32), 256, 0, stream>>>(xb, wqkvb, b_qkv, Qh, Kh, Vt);
  attn_kernel<<<dim3(32, 16), 512, 0, stream>>>(Qh, Kh, Vt, Hd);
  out_gemm<<<dim3(8, 64), 256, 0, stream>>>(Hd, wob, b_o, x, out);
}

// Round 6
// 200.349 us; speedup vs baseline: 2.4421x; 1.0201x over previous
//
#include <hip/hip_runtime.h>
#include <hip/hip_bf16.h>
#include <stdint.h>

typedef _Float16 half_t;
typedef _Float16 half4 __attribute__((ext_vector_type(4)));
typedef _Float16 half8 __attribute__((ext_vector_type(8)));
typedef float f32x4 __attribute__((ext_vector_type(4)));

// Q prescale: 1/sqrt(1024) * log2(e)  -> softmax computed in exp2 space
#define SCALE2_ 0.045084220f

#if __has_builtin(__builtin_amdgcn_exp2f)
#define EXP2F(x) __builtin_amdgcn_exp2f(x)
#else
#define EXP2F(x) exp2f(x)
#endif

#define GLL16(g, l)                                                        \
  __builtin_amdgcn_global_load_lds(                                        \
      (const __attribute__((address_space(1))) void*)(g),                  \
      (__attribute__((address_space(3))) void*)(l), 16, 0, 0)

#define WAITVM(N) asm volatile("s_waitcnt vmcnt(" #N ")" ::: "memory")
#define BAR() __builtin_amdgcn_s_barrier()
#define SCHEDB() __builtin_amdgcn_sched_barrier(0)

// ---------------------------------------------------------------- converts
__global__ void cvt_all(const float* __restrict__ x,
                        const float* __restrict__ wqkv,
                        const float* __restrict__ wo,
                        half_t* __restrict__ xb,
                        half_t* __restrict__ wqkvb,
                        half_t* __restrict__ wob) {
  int i = blockIdx.x * blockDim.x + threadIdx.x;
  const float* src; half_t* dst; int off;
  if (i < 1048576)       { src = x;    dst = xb;    off = i; }
  else if (i < 1835008)  { src = wqkv; dst = wqkvb; off = i - 1048576; }
  else                   { src = wo;   dst = wob;   off = i - 1835008; }
  float4 v = ((const float4*)src)[off];
  half4 h;
  h[0] = (half_t)v.x; h[1] = (half_t)v.y; h[2] = (half_t)v.z; h[3] = (half_t)v.w;
  ((half4*)dst)[off] = h;
}

// ---------------------------------------------------------------- QKV GEMM
// 128x128 tile, BK=64, XOR-swizzled LDS, double-buffered, counted vmcnt.
__global__ __launch_bounds__(256) void qkv_gemm(
    const half_t* __restrict__ A, const half_t* __restrict__ Bw,
    const float* __restrict__ bias,
    half_t* __restrict__ Qh, half_t* __restrict__ Kh, half_t* __restrict__ Vt) {
  __shared__ __align__(16) half_t As[2][128 * 64];
  __shared__ __align__(16) half_t Bs[2][128 * 64];
  const int tid = threadIdx.x;
  const int wave = tid >> 6, lane = tid & 63;
  const int t = lane & 15, g = lane >> 4;
  const int wr = (wave >> 1) * 64, wc = (wave & 1) * 64;
  // XCD swizzle: 768 blocks, 96 consecutive logical tiles per XCD
  const int hw = blockIdx.x;
  const int swzid = (hw & 7) * 96 + (hw >> 3);
  const int m0 = (swzid / 24) * 128, n0 = (swzid % 24) * 128;

  f32x4 acc[4][4];
#pragma unroll
  for (int i = 0; i < 4; ++i)
#pragma unroll
    for (int j = 0; j < 4; ++j) acc[i][j] = (f32x4){0.f, 0.f, 0.f, 0.f};

  const int r0 = tid >> 3;                                  // 0..31
  const int colb = ((tid & 7) * 16) ^ ((r0 & 7) << 4);
  const half_t* aptr = A + (size_t)(m0 + r0) * 1024 + (colb >> 1);
  const half_t* bptr = Bw + (size_t)(n0 + r0) * 1024 + (colb >> 1);
  const int swz = (t & 7) << 4;

#define QSTG(b, kkt)                                                          \
  {                                                                           \
    _Pragma("unroll")                                                         \
    for (int is = 0; is < 4; ++is) {                                          \
      GLL16(aptr + (size_t)(kkt) * 64 + (size_t)is * 32 * 1024,               \
            (char*)As + (b) * 16384 + wave * 1024 + is * 4096);               \
      GLL16(bptr + (size_t)(kkt) * 64 + (size_t)is * 32 * 1024,               \
            (char*)Bs + (b) * 16384 + wave * 1024 + is * 4096);               \
    }                                                                         \
  }

  QSTG(0, 0);
  for (int kk = 0; kk < 16; ++kk) {
    QSTG((kk + 1) & 1, (kk + 1) & 15);   // uniform count: 8 in flight
    WAITVM(8);                            // tile kk's 8 loads done
    BAR(); SCHEDB();
    const char* as = (const char*)As + (kk & 1) * 16384;
    const char* bs = (const char*)Bs + (kk & 1) * 16384;
#pragma unroll
    for (int h = 0; h < 2; ++h) {
      half8 af[4], bf[4];
#pragma unroll
      for (int fm = 0; fm < 4; ++fm)
        af[fm] = *(const half8*)(as + (wr + fm * 16 + t) * 128 +
                                 ((h * 64 + g * 16) ^ swz));
#pragma unroll
      for (int fn = 0; fn < 4; ++fn)
        bf[fn] = *(const half8*)(bs + (wc + fn * 16 + t) * 128 +
                                 ((h * 64 + g * 16) ^ swz));
#pragma unroll
      for (int fm = 0; fm < 4; ++fm)
#pragma unroll
        for (int fn = 0; fn < 4; ++fn)
          acc[fm][fn] = __builtin_amdgcn_mfma_f32_16x16x32_f16(
              af[fm], bf[fn], acc[fm][fn], 0, 0, 0);
    }
    BAR();  // all waves done reading buf kk before next overwrite
  }
#undef QSTG

#pragma unroll
  for (int fm = 0; fm < 4; ++fm) {
    const int mb = m0 + wr + fm * 16 + g * 4;
#pragma unroll
    for (int fn = 0; fn < 4; ++fn) {
      const int n = n0 + wc + fn * 16 + t;
      const float bv = bias[n];
      const int sec = n >> 10, nn = n & 1023;
      const int h = nn >> 6, c = nn & 63;
#pragma unroll
      for (int r = 0; r < 4; ++r) {
        const int mm = mb + r;
        const int b = mm >> 11, l = mm & 2047;
        const float v = acc[fm][fn][r] + bv;
        const size_t bh = (size_t)(b * 16 + h);
        if (sec == 0)      Qh[(bh * 2048 + l) * 64 + c] = (half_t)(v * SCALE2_);
        else if (sec == 1) Kh[(bh * 2048 + l) * 64 + c] = (half_t)v;
        else {
          // permute column within its 64-tile so PV reads are contiguous b128
          const int lp = (l & ~63) |
                         (((l >> 2) & 3) * 16 + ((l >> 4) & 3) * 4 + (l & 3));
          Vt[(bh * 64 + c) * 2048 + lp] = (half_t)v;
        }
      }
    }
  }
}

// ---------------------------------------------------------------- attention
// 8 waves/block, 128 q-rows; fixed-max softmax (C-init = -8, exact algebra);
// double-buffered K/V, counted vmcnt(2), raw barriers, XCD swizzle.
__global__ __launch_bounds__(512) void attn_kernel(
    const half_t* __restrict__ Qh, const half_t* __restrict__ Kh,
    const half_t* __restrict__ Vt, half_t* __restrict__ Hd) {
  __shared__ __align__(16) char lds_raw[2][2][8192];  // [buf][K=0/V=1][8KB]
  const int hw = blockIdx.x;                 // 0..511
  const int swzid = (hw & 7) * 64 + (hw >> 3);
  const int bh = swzid >> 4;                 // 4 heads per XCD -> K/V L2-fit
  const int qt = swzid & 15;
  const int tid = threadIdx.x;
  const int wave = tid >> 6, lane = tid & 63;
  const int t = lane & 15, g = lane >> 4;

  const half_t* Q = Qh + ((size_t)bh * 2048 + qt * 128 + wave * 16) * 64;
  const half8 q0 = *(const half8*)&Q[t * 64 + g * 8];
  const half8 q1 = *(const half8*)&Q[t * 64 + 32 + g * 8];

  const int r0 = tid >> 3;                                   // 0..63
  const int colb = ((tid & 7) * 16) ^ ((r0 & 7) << 4);
  const half_t* kbase = Kh + (size_t)bh * 2048 * 64 + (size_t)r0 * 64 + (colb >> 1);
  const half_t* vbase = Vt + (size_t)bh * 64 * 2048 + (size_t)r0 * 2048 + (colb >> 1);

  const int swz = (t & 7) << 4;
  const int vk0 = t * 128 + ((g * 16) ^ swz);
  const int vk1 = t * 128 + ((64 + g * 16) ^ swz);
  const int vv0 = t * 128 + ((g * 32) ^ swz);
  const int vv1 = t * 128 + ((g * 32 + 16) ^ swz);

  f32x4 o[4];
#pragma unroll
  for (int i = 0; i < 4; ++i) o[i] = (f32x4){0.f, 0.f, 0.f, 0.f};
  float lsum = 0.f;
  const f32x4 cinit = (f32x4){-8.f, -8.f, -8.f, -8.f};

#define STG(b, tt)                                                     \
  {                                                                    \
    GLL16(kbase + (size_t)(tt) * 4096, (char*)lds_raw[b][0] + wave * 1024); \
    GLL16(vbase + (size_t)(tt) * 64,   (char*)lds_raw[b][1] + wave * 1024); \
  }

  STG(0, 0);
  for (int it = 0; it < 32; ++it) {
    STG((it + 1) & 1, (it + 1) & 31);  // uniform: 2 newest in flight
    WAITVM(2);                          // tile it's 2 loads done
    BAR(); SCHEDB();

    const char* kb = lds_raw[it & 1][0];
    const char* vb = lds_raw[it & 1][1];

    // S^T - 8 = K*Q^T + C(-8): lane holds s[q=t][m = st*16 + g*4 + r]
    f32x4 s4[4];
    __builtin_amdgcn_s_setprio(1);
#pragma unroll
    for (int st = 0; st < 4; ++st) {
      half8 k0 = *(const half8*)(kb + vk0 + st * 2048);
      half8 k1 = *(const half8*)(kb + vk1 + st * 2048);
      f32x4 a = __builtin_amdgcn_mfma_f32_16x16x32_f16(k0, q0, cinit, 0, 0, 0);
      a = __builtin_amdgcn_mfma_f32_16x16x32_f16(k1, q1, a, 0, 0, 0);
      s4[st] = a;
    }
    __builtin_amdgcn_s_setprio(0);

    // fixed-max softmax: p = exp2(s - 8), l accumulated per-lane
    half4 pf[4];
#pragma unroll
    for (int st = 0; st < 4; ++st) {
      const float p0 = EXP2F(s4[st][0]);
      const float p1 = EXP2F(s4[st][1]);
      const float p2 = EXP2F(s4[st][2]);
      const float p3 = EXP2F(s4[st][3]);
      lsum += (p0 + p1) + (p2 + p3);
      pf[st][0] = (half_t)p0; pf[st][1] = (half_t)p1;
      pf[st][2] = (half_t)p2; pf[st][3] = (half_t)p3;
    }

    // PV: D[row=q][col=c] += P * V
    __builtin_amdgcn_s_setprio(1);
#pragma unroll
    for (int sthalf = 0; sthalf < 2; ++sthalf) {
      const int voff = sthalf ? vv1 : vv0;
#pragma unroll
      for (int ct = 0; ct < 4; ++ct) {
        half8 vv = *(const half8*)(vb + voff + ct * 2048);
        half4 vlo = {vv[0], vv[1], vv[2], vv[3]};
        half4 vhi = {vv[4], vv[5], vv[6], vv[7]};
        o[ct] = __builtin_amdgcn_mfma_f32_16x16x16f16(pf[2 * sthalf], vlo,
                                                      o[ct], 0, 0, 0);
        o[ct] = __builtin_amdgcn_mfma_f32_16x16x16f16(pf[2 * sthalf + 1], vhi,
                                                      o[ct], 0, 0, 0);
      }
    }
    __builtin_amdgcn_s_setprio(0);

    BAR();  // all waves done reading buf it before next overwrite
  }
#undef STG

  // one-time l reduction: sum over the 4 g-groups holding q=t
  lsum += __shfl_xor(lsum, 16);
  lsum += __shfl_xor(lsum, 32);

  const int b = bh >> 4, h = bh & 15;
#pragma unroll
  for (int r = 0; r < 4; ++r) {
    const float li = 1.f / __shfl(lsum, (g << 2) + r);
    const size_t row = (size_t)b * 2048 + qt * 128 + wave * 16 + g * 4 + r;
#pragma unroll
    for (int ct = 0; ct < 4; ++ct)
      Hd[row * 1024 + h * 64 + ct * 16 + t] = (half_t)(o[ct][r] * li);
  }
}

// ---------------------------------------------------------------- out GEMM
// 64x128 tile, BK=64, double-buffered, counted vmcnt, XCD swizzle.
__global__ __launch_bounds__(256) void out_gemm(
    const half_t* __restrict__ A, const half_t* __restrict__ Bw,
    const float* __restrict__ bias, const float* __restrict__ xres,
    float* __restrict__ out) {
  __shared__ __align__(16) half_t As[2][64 * 64];
  __shared__ __align__(16) half_t Bs[2][128 * 64];
  const int tid = threadIdx.x;
  const int wave = tid >> 6, lane = tid & 63;
  const int t = lane & 15, g = lane >> 4;
  const int wr = (wave >> 1) * 32, wc = (wave & 1) * 64;
  const int hw = blockIdx.x;                  // 512 blocks
  const int swzid = (hw & 7) * 64 + (hw >> 3);
  const int m0 = (swzid >> 3) * 64, n0 = (swzid & 7) * 128;  // B L2-reused

  f32x4 acc[2][4];
#pragma unroll
  for (int i = 0; i < 2; ++i)
#pragma unroll
    for (int j = 0; j < 4; ++j) acc[i][j] = (f32x4){0.f, 0.f, 0.f, 0.f};

  const int r0 = tid >> 3;
  const int colb = ((tid & 7) * 16) ^ ((r0 & 7) << 4);
  const half_t* aptr = A + (size_t)(m0 + r0) * 1024 + (colb >> 1);
  const half_t* bptr = Bw + (size_t)(n0 + r0) * 1024 + (colb >> 1);
  const int swz = (t & 7) << 4;

#define OSTG(b, kkt)                                                          \
  {                                                                           \
    _Pragma("unroll")                                                         \
    for (int is = 0; is < 2; ++is)                                            \
      GLL16(aptr + (size_t)(kkt) * 64 + (size_t)is * 32 * 1024,               \
            (char*)As + (b) * 8192 + wave * 1024 + is * 4096);                \
    _Pragma("unroll")                                                         \
    for (int is = 0; is < 4; ++is)                                            \
      GLL16(bptr + (size_t)(kkt) * 64 + (size_t)is * 32 * 1024,               \
            (char*)Bs + (b) * 16384 + wave * 1024 + is * 4096);               \
  }

  OSTG(0, 0);
  for (int kk = 0; kk < 16; ++kk) {
    OSTG((kk + 1) & 1, (kk + 1) & 15);
    WAITVM(6);
    BAR(); SCHEDB();
    const char* as = (const char*)As + (kk & 1) * 8192;
    const char* bs = (const char*)Bs + (kk & 1) * 16384;
#pragma unroll
    for (int h = 0; h < 2; ++h) {
      half8 af[2], bf[4];
#pragma unroll
      for (int fm = 0; fm < 2; ++fm)
        af[fm] = *(const half8*)(as + (wr + fm * 16 + t) * 128 +
                                 ((h * 64 + g * 16) ^ swz));
#pragma unroll
      for (int fn = 0; fn < 4; ++fn)
        bf[fn] = *(const half8*)(bs + (wc + fn * 16 + t) * 128 +
                                 ((h * 64 + g * 16) ^ swz));
#pragma unroll
      for (int fm = 0; fm < 2; ++fm)
#pragma unroll
        for (int fn = 0; fn < 4; ++fn)
          acc[fm][fn] = __builtin_amdgcn_mfma_f32_16x16x32_f16(
              af[fm], bf[fn], acc[fm][fn], 0, 0, 0);
    }
    BAR();
  }
#undef OSTG

#pragma unroll
  for (int fm = 0; fm < 2; ++fm) {
    const int mb = m0 + wr + fm * 16 + g * 4;
#pragma unroll
    for (int fn = 0; fn < 4; ++fn) {
      const int n = n0 + wc + fn * 16 + t;
      const float bv = bias[n];
#pragma unroll
      for (int r = 0; r < 4; ++r) {
        const size_t idx = (size_t)(mb + r) * 1024 + n;
        out[idx] = acc[fm][fn][r] + bv + xres[idx];
      }
    }
  }
}

// ---------------------------------------------------------------- launch
extern "C" void kernel_launch(void* const* d_in, const int* in_sizes, int n_in,
                              void* d_out, int out_size, void* d_ws, size_t ws_size,
                              hipStream_t stream) {
  const float* x     = (const float*)d_in[0];
  const float* w_qkv = (const float*)d_in[1];
  const float* b_qkv = (const float*)d_in[2];
  const float* w_o   = (const float*)d_in[3];
  const float* b_o   = (const float*)d_in[4];
  float* out = (float*)d_out;

  char* ws = (char*)d_ws;
  half_t* xb    = (half_t*)(ws + 0);                     // 8 MB
  half_t* wqkvb = (half_t*)(ws + (size_t)8  * 1048576);  // 6 MB
  half_t* wob   = (half_t*)(ws + (size_t)14 * 1048576);  // 2 MB
  half_t* Qh    = (half_t*)(ws + (size_t)16 * 1048576);  // 8 MB
  half_t* Kh    = (half_t*)(ws + (size_t)24 * 1048576);  // 8 MB
  half_t* Vt    = (half_t*)(ws + (size_t)32 * 1048576);  // 8 MB
  half_t* Hd    = (half_t*)(ws + (size_t)40 * 1048576);  // 8 MB

  cvt_all<<<8192, 256, 0, stream>>>(x, w_qkv, w_o, xb, wqkvb, wob);
  qkv_gemm<<<768, 256, 0, stream>>>(xb, wqkvb, b_qkv, Qh, Kh, Vt);
  attn_kernel<<<512, 512, 0, stream>>>(Qh, Kh, Vt, Hd);
  out_gemm<<<512, 256, 0, stream>>>(Hd, wob, b_o, x, out);
}